// Round 6
// baseline (107.935 us; speedup 1.0000x reference)
//
#include <hip/hip_runtime.h>
#include <hip/hip_bf16.h>
#include <stdint.h>

typedef __attribute__((ext_vector_type(8))) __bf16 bf16x8;
typedef __attribute__((ext_vector_type(4))) float f32x4;
typedef __attribute__((ext_vector_type(8))) unsigned short u16x8;

__device__ __forceinline__ unsigned short f2bf(float f) {
    unsigned u = __builtin_bit_cast(unsigned, f);
    return (unsigned short)((u + 0x7fffu + ((u >> 16) & 1u)) >> 16);  // RNE
}

__device__ __forceinline__ void glds16(const void* g, void* l) {
    __builtin_amdgcn_global_load_lds(
        (const __attribute__((address_space(1))) unsigned int*)(uintptr_t)g,
        (__attribute__((address_space(3))) unsigned int*)l, 16, 0, 0);
}

#define VMCNT(n) asm volatile("s_waitcnt vmcnt(" #n ")" ::: "memory")
#define BAR()                                  \
    do {                                       \
        asm volatile("" ::: "memory");         \
        __builtin_amdgcn_s_barrier();          \
        asm volatile("" ::: "memory");         \
    } while (0)

// ---------------------------------------------------------------------------
// Kernel 1: MFMA-ready slabs for the W-construction GEMM (K=16 padded to 32).
//   Aslab[bo][m][32]: m = o01l*64+a01, k = b*4+q, val = F0*F1
//   Bslab[bn4][n][32]: n = o23l*64+a23, val = sum_{r2,r3} F2*F3*core
// ---------------------------------------------------------------------------
__global__ __launch_bounds__(256) void prep_slabs(const float* __restrict__ factors,
                                                  const float* __restrict__ cores,
                                                  unsigned short* __restrict__ Aslab,
                                                  unsigned short* __restrict__ Bslab) {
    int idx = blockIdx.x * 256 + threadIdx.x;   // 0 .. 131071
    int e = idx & 65535;
    int grp = e >> 12;                           // bo or bn4 (0..15)
    int m = (e >> 4) & 255;                      // row in slab
    int k = e & 15;                              // (b,q)
    int b = k >> 2, q = k & 3, r0 = q >> 1, r1 = q & 1;
    int base = (e >> 4) * 32;
    if (idx < 65536) {
        int o01 = grp * 4 + (m >> 6), a01 = m & 63;
        int o0 = o01 >> 3, o1 = o01 & 7, a0 = a01 >> 3, a1 = a01 & 7;
        float v = factors[b*512 +   0 + a0*16 + o0*2 + r0]
                * factors[b*512 + 128 + a1*16 + o1*2 + r1];
        Aslab[base + k] = f2bf(v);
        Aslab[base + k + 16] = 0;
    } else {
        int o23 = grp * 4 + (m >> 6), a23 = m & 63;
        int o2 = o23 >> 3, o3 = o23 & 7, a2 = a23 >> 3, a3 = a23 & 7;
        float s = 0.f;
#pragma unroll
        for (int r2 = 0; r2 < 2; ++r2)
#pragma unroll
            for (int r3 = 0; r3 < 2; ++r3)
                s += factors[b*512 + 256 + a2*16 + o2*2 + r2]
                   * factors[b*512 + 384 + a3*16 + o3*2 + r3]
                   * cores[b*16 + r3*8 + r2*4 + r1*2 + r0];
        Bslab[base + k] = f2bf(s);
        Bslab[base + k + 16] = 0;
    }
}

// ---------------------------------------------------------------------------
// Kernel 2: convert x (f32) -> bf16
// ---------------------------------------------------------------------------
__global__ __launch_bounds__(256) void cvt_bf16(const float4* __restrict__ in,
                                                ushort4* __restrict__ out) {
    int i = blockIdx.x * 256 + threadIdx.x;     // exactly 1048576 threads
    float4 v = in[i];
    ushort4 o;
    o.x = f2bf(v.x); o.y = f2bf(v.y); o.z = f2bf(v.z); o.w = f2bf(v.w);
    out[i] = o;
}

// ---------------------------------------------------------------------------
// Kernel 3: W build as 4096x4096x16 MFMA GEMM (K padded to 32).
// ---------------------------------------------------------------------------
__global__ __launch_bounds__(256) void build_w2(const unsigned short* __restrict__ Aslab,
                                                const unsigned short* __restrict__ Bslab,
                                                unsigned short* __restrict__ Wt) {
    __shared__ unsigned short As2[256 * 40];     // rows padded to 40 elems
    __shared__ unsigned short Bs2[256 * 40];
    __shared__ unsigned short lbuf[4 * 64 * 72];
    const int tid = threadIdx.x, lane = tid & 63, w = tid >> 6;
    const int bo = blockIdx.x >> 4, bn4 = blockIdx.x & 15;

    const u16x8* srcA = (const u16x8*)(Aslab + ((size_t)bo * 256 + tid) * 32);
    const u16x8* srcB = (const u16x8*)(Bslab + ((size_t)bn4 * 256 + tid) * 32);
#pragma unroll
    for (int i = 0; i < 4; ++i) {
        *(u16x8*)&As2[tid * 40 + i * 8] = srcA[i];
        *(u16x8*)&Bs2[tid * 40 + i * 8] = srcB[i];
    }
    __syncthreads();

    const int fr = lane & 15, fh = lane >> 4;
    bf16x8 af[4];
#pragma unroll
    for (int mf = 0; mf < 4; ++mf)
        af[mf] = *(const bf16x8*)&As2[(w * 64 + mf * 16 + fr) * 40 + fh * 8];

    for (int wn = 0; wn < 4; ++wn) {
        f32x4 acc[4][4] = {};
        bf16x8 bf_[4];
#pragma unroll
        for (int nf = 0; nf < 4; ++nf)
            bf_[nf] = *(const bf16x8*)&Bs2[(wn * 64 + nf * 16 + fr) * 40 + fh * 8];
#pragma unroll
        for (int mf = 0; mf < 4; ++mf)
#pragma unroll
            for (int nf = 0; nf < 4; ++nf)
                acc[mf][nf] = __builtin_amdgcn_mfma_f32_16x16x32_bf16(
                    af[mf], bf_[nf], acc[mf][nf], 0, 0, 0);
#pragma unroll
        for (int mf = 0; mf < 4; ++mf)
#pragma unroll
            for (int nf = 0; nf < 4; ++nf)
#pragma unroll
                for (int j = 0; j < 4; ++j)
                    lbuf[w * 4608 + (mf * 16 + fh * 4 + j) * 72 + nf * 16 + fr] =
                        f2bf(acc[mf][nf][j]);
        const int o = (bo * 4 + w) * 64 + bn4 * 4 + wn;
        unsigned short* dst = Wt + (size_t)o * 4096;
#pragma unroll
        for (int i = 0; i < 8; ++i) {
            int c = i * 64 + lane;
            *(u16x8*)&dst[c * 8] =
                *(const u16x8*)&lbuf[w * 4608 + (c >> 3) * 72 + (c & 7) * 8];
        }
    }
}

// ---------------------------------------------------------------------------
// Kernel 4a: zero C (atomics epilogue needs zeros; harness poisons d_out)
// ---------------------------------------------------------------------------
__global__ __launch_bounds__(256) void zero_f32(float4* __restrict__ p, int n4) {
    int i = blockIdx.x * 256 + threadIdx.x;
    int stride = gridDim.x * 256;
    for (; i < n4; i += stride) p[i] = float4{0.f, 0.f, 0.f, 0.f};
}

// ---------------------------------------------------------------------------
// Kernel 4b: C += A * Wt^T over K-chunk.  v6 — 8-wave 256^2 structure:
//   tile 256x256, BK=64, 8 waves (2M x 4N), per-wave 128x64, acc 8x4.
//   512 threads = 2 waves/SIMD: TLP covers lgkm/vm stalls (the R5 kernel at
//   1 wave/SIMD measured 2475 cyc/step vs a 512-cyc MFMA floor — all exposed
//   stall; MfmaUtil 20.6% == 512/2475 exactly).
//   Double-buffered LDS 2x64KB, counted vmcnt(8) (never 0 in loop), raw
//   s_barrier, s_setprio(1) around MFMA clusters (role-split exists now).
//   Source-side XOR chunk swizzle (key (row>>1)&7, i-invariant) - rule 21.
//   Split-K x4 (KCH=1024) restores grid=256; f32 atomicAdd epilogue.
//   XCD map: xcd owns bn-pair (4MB of W, L2-resident, all 4 ks local).
// ---------------------------------------------------------------------------
__global__ __launch_bounds__(512, 2) void gemm_bt8(const unsigned short* __restrict__ A,
                                                   const unsigned short* __restrict__ Bt,
                                                   float* __restrict__ C) {
    constexpr int K = 4096;
    constexpr int N = 4096;
    constexpr int BK = 64;
    constexpr int KCH = 1024;
    constexpr int NT = KCH / BK;                 // 16 K-steps
    __shared__ alignas(16) char lds[2][65536];   // [buf][A 32KB | B 32KB]
    const int tid = threadIdx.x;
    const int lane = tid & 63, wid = tid >> 6;   // 8 waves
    const int wr = wid >> 2, wc = wid & 3;       // 2M x 4N
    const int xcd = blockIdx.x & 7, r = blockIdx.x >> 3;  // r 0..31
    const int bn = xcd * 2 + (r & 1);            // 0..15
    const int bm = (r >> 1) & 3;                 // 0..3
    const int ks = r >> 3;                       // 0..3

    // --- staging: per tile A = 2048 16B slots, B = 2048; 4+4 per thread ---
    // slot cs = i*512 + tid: row = cs>>3, phys chunk cs&7, logical c = p^key;
    // key (row>>1)&7 is i-invariant (i steps rows by 64).
    const unsigned short* gA[4]; const unsigned short* gB[4];
    int lAoff[4], lBoff[4];
#pragma unroll
    for (int i = 0; i < 4; ++i) {
        int cs = i * 512 + tid;
        int row = cs >> 3;
        int c = (cs & 7) ^ ((row >> 1) & 7);
        gA[i] = A  + (size_t)(bm * 256 + row) * K + ks * KCH + c * 8;
        gB[i] = Bt + (size_t)(bn * 256 + row) * K + ks * KCH + c * 8;
        lAoff[i] = i * 8192 + wid * 1024;        // wave-uniform base (+lane*16 HW)
        lBoff[i] = 32768 + i * 8192 + wid * 1024;
    }

#define STAGE(buf, kt)                                                        \
    do {                                                                      \
        _Pragma("unroll")                                                     \
        for (int i = 0; i < 4; ++i) glds16(gA[i] + (kt), &lds[buf][lAoff[i]]);\
        _Pragma("unroll")                                                     \
        for (int i = 0; i < 4; ++i) glds16(gB[i] + (kt), &lds[buf][lBoff[i]]);\
    } while (0)

    // --- fragment read offsets (swizzled, m/n folded into imm offsets) ---
    const int fr = lane & 15, fh = lane >> 4;
    const int sk = (fr >> 1) & 7;
    int aoff[2], boff[2];
#pragma unroll
    for (int kk = 0; kk < 2; ++kk) {
        aoff[kk] = (wr * 128 + fr) * 128 + (((kk * 4 + fh) ^ sk) << 4);
        boff[kk] = 32768 + (wc * 64 + fr) * 128 + (((kk * 4 + fh) ^ sk) << 4);
    }

    f32x4 acc[8][4] = {};

#define COMPUTE(buf)                                                          \
    do {                                                                      \
        const char* base = &lds[buf][0];                                      \
        _Pragma("unroll")                                                     \
        for (int kk = 0; kk < 2; ++kk) {                                      \
            bf16x8 bf4[4], af8[8];                                            \
            _Pragma("unroll")                                                 \
            for (int n = 0; n < 4; ++n)                                       \
                bf4[n] = *(const bf16x8*)(base + boff[kk] + n * 2048);        \
            _Pragma("unroll")                                                 \
            for (int m = 0; m < 8; ++m)                                       \
                af8[m] = *(const bf16x8*)(base + aoff[kk] + m * 2048);        \
            __builtin_amdgcn_s_setprio(1);                                    \
            _Pragma("unroll")                                                 \
            for (int m = 0; m < 8; ++m)                                       \
                _Pragma("unroll")                                             \
                for (int n = 0; n < 4; ++n)                                   \
                    acc[m][n] = __builtin_amdgcn_mfma_f32_16x16x32_bf16(      \
                        af8[m], bf4[n], acc[m][n], 0, 0, 0);                  \
            __builtin_amdgcn_s_setprio(0);                                    \
        }                                                                     \
    } while (0)

    // --- depth-1 pipelined loop, counted vmcnt ---
    STAGE(0, 0);
    for (int t = 0; t < NT - 1; ++t) {
        STAGE((t + 1) & 1, (t + 1) * BK);   // +8 -> 16 outstanding
        VMCNT(8);                            // tile t's 8 loads landed (this wave)
        BAR();                               // -> landed for ALL waves
        COMPUTE(t & 1);
        BAR();                               // readers done before next STAGE
    }
    VMCNT(0);
    BAR();
    COMPUTE((NT - 1) & 1);

    // --- epilogue: f32 atomic accumulate (4-way split-K) ---
    const int crow0 = bm * 256 + wr * 128 + fh * 4;
    const int ccol0 = bn * 256 + wc * 64 + fr;
#pragma unroll
    for (int m = 0; m < 8; ++m)
#pragma unroll
        for (int n = 0; n < 4; ++n)
#pragma unroll
            for (int j = 0; j < 4; ++j)
                atomicAdd(&C[(size_t)(crow0 + m * 16 + j) * N + (ccol0 + n * 16)],
                          acc[m][n][j]);
#undef STAGE
#undef COMPUTE
}

// ---------------------------------------------------------------------------
extern "C" void kernel_launch(void* const* d_in, const int* in_sizes, int n_in,
                              void* d_out, int out_size, void* d_ws, size_t ws_size,
                              hipStream_t stream) {
    const float* inputs  = (const float*)d_in[0];   // [1024, 4096] f32
    const float* cores   = (const float*)d_in[1];   // [4, 16] f32
    const float* factors = (const float*)d_in[2];   // [4,4,8,8,2] f32
    float* out = (float*)d_out;                     // [1024, 4096] f32

    char* ws = (char*)d_ws;
    unsigned short* xb    = (unsigned short*)ws;                    //  8 MB bf16 x
    unsigned short* Wt    = (unsigned short*)(ws + (8u << 20));     // 32 MB bf16 W^T
    unsigned short* Aslab = (unsigned short*)(ws + (40u << 20));    // 256 KB
    unsigned short* Bslab = Aslab + 131072;                         // 256 KB

    prep_slabs<<<512, 256, 0, stream>>>(factors, cores, Aslab, Bslab);
    cvt_bf16<<<4096, 256, 0, stream>>>((const float4*)inputs, (ushort4*)xb);
    build_w2<<<256, 256, 0, stream>>>(Aslab, Bslab, Wt);
    zero_f32<<<2048, 256, 0, stream>>>((float4*)out, out_size / 4);
    gemm_bt8<<<256, 512, 0, stream>>>(xb, Wt, out);
}

// Round 7
// 64.115 us; speedup vs baseline: 1.6835x; 1.6835x over previous
//
#include <hip/hip_runtime.h>
#include <hip/hip_bf16.h>
#include <stdint.h>

typedef __attribute__((ext_vector_type(8))) __bf16 bf16x8;
typedef __attribute__((ext_vector_type(4))) float f32x4;
typedef __attribute__((ext_vector_type(8))) unsigned short u16x8;

__device__ __forceinline__ unsigned short f2bf(float f) {
    unsigned u = __builtin_bit_cast(unsigned, f);
    return (unsigned short)((u + 0x7fffu + ((u >> 16) & 1u)) >> 16);  // RNE
}

__device__ __forceinline__ void glds16(const void* g, void* l) {
    __builtin_amdgcn_global_load_lds(
        (const __attribute__((address_space(1))) unsigned int*)(uintptr_t)g,
        (__attribute__((address_space(3))) unsigned int*)l, 16, 0, 0);
}

#define VMCNT(n) asm volatile("s_waitcnt vmcnt(" #n ")" ::: "memory")
#define BAR()                                  \
    do {                                       \
        asm volatile("" ::: "memory");         \
        __builtin_amdgcn_s_barrier();          \
        asm volatile("" ::: "memory");         \
    } while (0)

// ---------------------------------------------------------------------------
// Kernel 1: MFMA-ready slabs for the W-construction GEMM (K=16 padded to 32).
//   Aslab[bo][m][32]: m = o01l*64+a01, k = b*4+q, val = F0*F1
//   Bslab[bn4][n][32]: n = o23l*64+a23, val = sum_{r2,r3} F2*F3*core
// ---------------------------------------------------------------------------
__global__ __launch_bounds__(256) void prep_slabs(const float* __restrict__ factors,
                                                  const float* __restrict__ cores,
                                                  unsigned short* __restrict__ Aslab,
                                                  unsigned short* __restrict__ Bslab) {
    int idx = blockIdx.x * 256 + threadIdx.x;   // 0 .. 131071
    int e = idx & 65535;
    int grp = e >> 12;                           // bo or bn4 (0..15)
    int m = (e >> 4) & 255;                      // row in slab
    int k = e & 15;                              // (b,q)
    int b = k >> 2, q = k & 3, r0 = q >> 1, r1 = q & 1;
    int base = (e >> 4) * 32;
    if (idx < 65536) {
        int o01 = grp * 4 + (m >> 6), a01 = m & 63;
        int o0 = o01 >> 3, o1 = o01 & 7, a0 = a01 >> 3, a1 = a01 & 7;
        float v = factors[b*512 +   0 + a0*16 + o0*2 + r0]
                * factors[b*512 + 128 + a1*16 + o1*2 + r1];
        Aslab[base + k] = f2bf(v);
        Aslab[base + k + 16] = 0;
    } else {
        int o23 = grp * 4 + (m >> 6), a23 = m & 63;
        int o2 = o23 >> 3, o3 = o23 & 7, a2 = a23 >> 3, a3 = a23 & 7;
        float s = 0.f;
#pragma unroll
        for (int r2 = 0; r2 < 2; ++r2)
#pragma unroll
            for (int r3 = 0; r3 < 2; ++r3)
                s += factors[b*512 + 256 + a2*16 + o2*2 + r2]
                   * factors[b*512 + 384 + a3*16 + o3*2 + r3]
                   * cores[b*16 + r3*8 + r2*4 + r1*2 + r0];
        Bslab[base + k] = f2bf(s);
        Bslab[base + k + 16] = 0;
    }
}

// ---------------------------------------------------------------------------
// Kernel 2: convert x (f32) -> bf16
// ---------------------------------------------------------------------------
__global__ __launch_bounds__(256) void cvt_bf16(const float4* __restrict__ in,
                                                ushort4* __restrict__ out) {
    int i = blockIdx.x * 256 + threadIdx.x;     // exactly 1048576 threads
    float4 v = in[i];
    ushort4 o;
    o.x = f2bf(v.x); o.y = f2bf(v.y); o.z = f2bf(v.z); o.w = f2bf(v.w);
    out[i] = o;
}

// ---------------------------------------------------------------------------
// Kernel 3: W build as 4096x4096x16 MFMA GEMM (K padded to 32).
// ---------------------------------------------------------------------------
__global__ __launch_bounds__(256) void build_w2(const unsigned short* __restrict__ Aslab,
                                                const unsigned short* __restrict__ Bslab,
                                                unsigned short* __restrict__ Wt) {
    __shared__ unsigned short As2[256 * 40];     // rows padded to 40 elems
    __shared__ unsigned short Bs2[256 * 40];
    __shared__ unsigned short lbuf[4 * 64 * 72];
    const int tid = threadIdx.x, lane = tid & 63, w = tid >> 6;
    const int bo = blockIdx.x >> 4, bn4 = blockIdx.x & 15;

    const u16x8* srcA = (const u16x8*)(Aslab + ((size_t)bo * 256 + tid) * 32);
    const u16x8* srcB = (const u16x8*)(Bslab + ((size_t)bn4 * 256 + tid) * 32);
#pragma unroll
    for (int i = 0; i < 4; ++i) {
        *(u16x8*)&As2[tid * 40 + i * 8] = srcA[i];
        *(u16x8*)&Bs2[tid * 40 + i * 8] = srcB[i];
    }
    __syncthreads();

    const int fr = lane & 15, fh = lane >> 4;
    bf16x8 af[4];
#pragma unroll
    for (int mf = 0; mf < 4; ++mf)
        af[mf] = *(const bf16x8*)&As2[(w * 64 + mf * 16 + fr) * 40 + fh * 8];

    for (int wn = 0; wn < 4; ++wn) {
        f32x4 acc[4][4] = {};
        bf16x8 bf_[4];
#pragma unroll
        for (int nf = 0; nf < 4; ++nf)
            bf_[nf] = *(const bf16x8*)&Bs2[(wn * 64 + nf * 16 + fr) * 40 + fh * 8];
#pragma unroll
        for (int mf = 0; mf < 4; ++mf)
#pragma unroll
            for (int nf = 0; nf < 4; ++nf)
                acc[mf][nf] = __builtin_amdgcn_mfma_f32_16x16x32_bf16(
                    af[mf], bf_[nf], acc[mf][nf], 0, 0, 0);
#pragma unroll
        for (int mf = 0; mf < 4; ++mf)
#pragma unroll
            for (int nf = 0; nf < 4; ++nf)
#pragma unroll
                for (int j = 0; j < 4; ++j)
                    lbuf[w * 4608 + (mf * 16 + fh * 4 + j) * 72 + nf * 16 + fr] =
                        f2bf(acc[mf][nf][j]);
        const int o = (bo * 4 + w) * 64 + bn4 * 4 + wn;
        unsigned short* dst = Wt + (size_t)o * 4096;
#pragma unroll
        for (int i = 0; i < 8; ++i) {
            int c = i * 64 + lane;
            *(u16x8*)&dst[c * 8] =
                *(const u16x8*)&lbuf[w * 4608 + (c >> 3) * 72 + (c & 7) * 8];
        }
    }
}

// ---------------------------------------------------------------------------
// Kernel 4: C[1024][4096] = A[1024][4096] * Wt^T.  v7:
//   tile 64(M) x 128(N), BK=64, 4 waves (2x2), wave-tile 32x64, acc 2x4.
//   Grid 512 = 2 blocks/CU: co-resident DESYNCHRONIZED blocks provide the
//   stall overlap (R1 vs R2 evidence: 1774 -> 487 cyc/block-step effective
//   at 4 blocks/CU; same-block waves lockstep at barriers and do NOT help).
//   LDS 3 x 24KB = 72KB <= 80KB so 2 blocks fit. Depth-2 pipeline, counted
//   vmcnt(12) (6 glds/stage), compile-time buffer rotation (3-unrolled).
//   Plain f32 stores (no atomics: R6 showed ~30us atomic cost).
//   Source-side XOR chunk swizzle (rule 21): phys chunk p of row r holds
//   logical chunk p ^ ((r>>1)&7); read side XORs sk=(fr>>1)&7 (16-row frag
//   steps keep the key invariant). Conflict-free verified (R3+: conflicts=0).
//   XCD map: xcd owns 4 bn (4MB of W, L2-resident); consecutive r share bm
//   so the 4 same-bm blocks on an XCD fetch each A-tile from L3 ~once.
// ---------------------------------------------------------------------------
__global__ __launch_bounds__(256, 2) void gemm_bt64(const unsigned short* __restrict__ A,
                                                    const unsigned short* __restrict__ Bt,
                                                    float* __restrict__ C) {
    constexpr int K = 4096;
    constexpr int N = 4096;
    constexpr int BK = 64;
    constexpr int NT = K / BK;                   // 64 K-steps
    __shared__ alignas(16) char lds[3][24576];   // [buf][A 8KB | B 16KB]
    const int tid = threadIdx.x;
    const int lane = tid & 63, w = tid >> 6;
    const int wm = w >> 1, wn = w & 1;
    const int xcd = blockIdx.x & 7, r = blockIdx.x >> 3;  // r 0..63
    const int bn = xcd * 4 + (r & 3);            // 0..31
    const int bm = r >> 2;                       // 0..15

    // --- staging: A = 512 16B slots (2/thread), B = 1024 (4/thread) ---
    // slot cs = i*256+tid: row = cs>>3, phys chunk cs&7, logical c = p^((row>>1)&7)
    // (i steps rows by 32 -> key invariant)
    const unsigned short* gA[2]; const unsigned short* gB[4];
    int lAoff[2], lBoff[4];
#pragma unroll
    for (int i = 0; i < 2; ++i) {
        int cs = i * 256 + tid;
        int row = cs >> 3;
        int c = (cs & 7) ^ ((row >> 1) & 7);
        gA[i] = A + (size_t)(bm * 64 + row) * K + c * 8;
        lAoff[i] = i * 4096 + w * 1024;          // wave-uniform base (+lane*16 HW)
    }
#pragma unroll
    for (int i = 0; i < 4; ++i) {
        int cs = i * 256 + tid;
        int row = cs >> 3;
        int c = (cs & 7) ^ ((row >> 1) & 7);
        gB[i] = Bt + (size_t)(bn * 128 + row) * K + c * 8;
        lBoff[i] = 8192 + i * 4096 + w * 1024;
    }

#define STAGE(buf, kt)                                                        \
    do {                                                                      \
        _Pragma("unroll")                                                     \
        for (int i = 0; i < 2; ++i) glds16(gA[i] + (kt), &lds[buf][lAoff[i]]);\
        _Pragma("unroll")                                                     \
        for (int i = 0; i < 4; ++i) glds16(gB[i] + (kt), &lds[buf][lBoff[i]]);\
    } while (0)

    // --- fragment read offsets (swizzled) ---
    const int fr = lane & 15, fh = lane >> 4;
    const int sk = (fr >> 1) & 7;
    int aoff[2], boff[2];
#pragma unroll
    for (int kk = 0; kk < 2; ++kk) {
        aoff[kk] = (wm * 32 + fr) * 128 + (((kk * 4 + fh) ^ sk) << 4);
        boff[kk] = 8192 + (wn * 64 + fr) * 128 + (((kk * 4 + fh) ^ sk) << 4);
    }

    f32x4 acc[2][4] = {};

#define COMPUTE(buf)                                                          \
    do {                                                                      \
        const char* base = &lds[buf][0];                                      \
        _Pragma("unroll")                                                     \
        for (int kk = 0; kk < 2; ++kk) {                                      \
            bf16x8 af2[2], bf4[4];                                            \
            _Pragma("unroll")                                                 \
            for (int m = 0; m < 2; ++m)                                       \
                af2[m] = *(const bf16x8*)(base + aoff[kk] + m * 2048);        \
            _Pragma("unroll")                                                 \
            for (int n = 0; n < 4; ++n)                                       \
                bf4[n] = *(const bf16x8*)(base + boff[kk] + n * 2048);        \
            _Pragma("unroll")                                                 \
            for (int m = 0; m < 2; ++m)                                       \
                _Pragma("unroll")                                             \
                for (int n = 0; n < 4; ++n)                                   \
                    acc[m][n] = __builtin_amdgcn_mfma_f32_16x16x32_bf16(      \
                        af2[m], bf4[n], acc[m][n], 0, 0, 0);                  \
        }                                                                     \
    } while (0)

#define PHASE(tb, sbuf, cbuf)                                                 \
    do {                                                                      \
        STAGE(sbuf, ((tb) + 2) * BK);                                         \
        VMCNT(12);                                                            \
        BAR();                                                                \
        COMPUTE(cbuf);                                                        \
        BAR();                                                                \
    } while (0)

    // --- depth-2 pipelined main loop (STAGE(s) targets buf s%3) ---
    STAGE(0, 0);
    STAGE(1, BK);
    for (int t = 0; t < 60; t += 3) {            // phases t, t+1, t+2
        PHASE(t, 2, 0);
        PHASE(t + 1, 0, 1);
        PHASE(t + 2, 1, 2);
    }
    PHASE(60, 2, 0);                             // stage 62, compute 60
    PHASE(61, 0, 1);                             // stage 63, compute 61
    VMCNT(6);  BAR(); COMPUTE(2); BAR();         // compute 62
    VMCNT(0);  BAR(); COMPUTE(0);                // compute 63

    // --- epilogue: plain coalesced stores ---
    const int crow0 = bm * 64 + wm * 32 + fh * 4;
    const int ccol0 = bn * 128 + wn * 64 + fr;
#pragma unroll
    for (int m = 0; m < 2; ++m)
#pragma unroll
        for (int n = 0; n < 4; ++n)
#pragma unroll
            for (int j = 0; j < 4; ++j)
                C[(size_t)(crow0 + m * 16 + j) * N + (ccol0 + n * 16)] = acc[m][n][j];
#undef STAGE
#undef COMPUTE
#undef PHASE
}

// ---------------------------------------------------------------------------
extern "C" void kernel_launch(void* const* d_in, const int* in_sizes, int n_in,
                              void* d_out, int out_size, void* d_ws, size_t ws_size,
                              hipStream_t stream) {
    const float* inputs  = (const float*)d_in[0];   // [1024, 4096] f32
    const float* cores   = (const float*)d_in[1];   // [4, 16] f32
    const float* factors = (const float*)d_in[2];   // [4,4,8,8,2] f32
    float* out = (float*)d_out;                     // [1024, 4096] f32

    char* ws = (char*)d_ws;
    unsigned short* xb    = (unsigned short*)ws;                    //  8 MB bf16 x
    unsigned short* Wt    = (unsigned short*)(ws + (8u << 20));     // 32 MB bf16 W^T
    unsigned short* Aslab = (unsigned short*)(ws + (40u << 20));    // 256 KB
    unsigned short* Bslab = Aslab + 131072;                         // 256 KB

    prep_slabs<<<512, 256, 0, stream>>>(factors, cores, Aslab, Bslab);
    cvt_bf16<<<4096, 256, 0, stream>>>((const float4*)inputs, (ushort4*)xb);
    build_w2<<<256, 256, 0, stream>>>(Aslab, Bslab, Wt);
    gemm_bt64<<<512, 256, 0, stream>>>(xb, Wt, out);
}